// Round 7
// baseline (213.842 us; speedup 1.0000x reference)
//
#include <hip/hip_runtime.h>

#define N_NODES 50000
#define N_EDGES 600000
#define HID 128
#define LN_EPS 1e-5f
#define MAXDEG 64
#define NB_GEMM1 782   // ceil(50000/64)
#define NB_PLACE 2344  // ceil(600000/256)

typedef __attribute__((ext_vector_type(8))) short short8;
typedef __attribute__((ext_vector_type(4))) float f32x4;

__device__ inline float b2f(unsigned short u) {
    union { unsigned int i; float f; } v;
    v.i = ((unsigned int)u) << 16;
    return v.f;
}
__device__ inline unsigned short f2b(float f) {   // round-to-nearest-even
    union { float f; unsigned int u; } v; v.f = f;
    unsigned int r = (v.u + 0x7FFFu + ((v.u >> 16) & 1u)) >> 16;
    return (unsigned short)r;
}

// ================= K0: prep — W1,W2 -> bf16 transposed in global; zero cursor =================
// replaces the hipMemsetAsync dispatch; 324 blocks, trivial.
__global__ __launch_bounds__(256) void k_prep(const float* __restrict__ W1,
                                              const float* __restrict__ W2,
                                              unsigned short* __restrict__ WT1,
                                              unsigned short* __restrict__ WT2,
                                              int* __restrict__ cursor) {
    const int bid = blockIdx.x, tid = threadIdx.x;
    if (bid < 64) {
        const int i = bid * 256 + tid;             // 16384 W1 elements
        WT1[(i & 127) * 128 + (i >> 7)] = f2b(W1[i]);
    } else if (bid < 128) {
        const int i = (bid - 64) * 256 + tid;      // 16384 W2 elements
        WT2[(i & 127) * 128 + (i >> 7)] = f2b(W2[i]);
    } else {
        const int i = (bid - 128) * 256 + tid;
        if (i < N_NODES) cursor[i] = 0;
    }
}

// ================= K1: GEMM1 (blocks [0,782), B direct from global/L2) + edge PLACE =================
// No LDS at all: place blocks get full occupancy; GEMM B-frags read from L2-hot WT1
// (782 blocks x 32KB = 25 MB aggregate L2 traffic -- same pattern as the FUSE WT2 reads).
__global__ __launch_bounds__(256) void k_fused1(const float* __restrict__ x,
                                                const unsigned short* __restrict__ WT1,
                                                const int* __restrict__ ei,
                                                int* __restrict__ cursor,
                                                int* __restrict__ esrc,
                                                unsigned short* __restrict__ hb) {
    const int tid = threadIdx.x;

    if (blockIdx.x >= NB_GEMM1) {
        const int e = (blockIdx.x - NB_GEMM1) * 256 + tid;
        if (e < N_EDGES) {
            const int d = ei[N_EDGES + e];
            const int pos = atomicAdd(&cursor[d], 1);
            if (pos < MAXDEG) esrc[d * MAXDEG + pos] = ei[e];
        }
        return;
    }

    // ---- GEMM1: hb[64x128](bf16) = bf16(x[64x128]) @ W1 ----
    const int lane = tid & 63;
    const int ln   = lane & 15;
    const int quad = lane >> 4;
    const int m0   = blockIdx.x * 64 + (tid >> 6) * 16;

    f32x4 acc[8];
#pragma unroll
    for (int t = 0; t < 8; ++t) acc[t] = (f32x4){0.f, 0.f, 0.f, 0.f};

    int arow = m0 + ln;
    if (arow >= N_NODES) arow = N_NODES - 1;
    const float* aptr = x + (size_t)arow * HID + quad * 8;
    const unsigned short* bptr = WT1 + (size_t)ln * HID + quad * 8;

#pragma unroll
    for (int ks = 0; ks < 4; ++ks) {
        const float4 v0 = *(const float4*)(aptr + ks * 32);
        const float4 v1 = *(const float4*)(aptr + ks * 32 + 4);
        short8 a;
        a[0] = (short)f2b(v0.x); a[1] = (short)f2b(v0.y);
        a[2] = (short)f2b(v0.z); a[3] = (short)f2b(v0.w);
        a[4] = (short)f2b(v1.x); a[5] = (short)f2b(v1.y);
        a[6] = (short)f2b(v1.z); a[7] = (short)f2b(v1.w);
#pragma unroll
        for (int t = 0; t < 8; ++t) {
            const short8 b = *(const short8*)(bptr + (size_t)t * 16 * HID + ks * 32);
            acc[t] = __builtin_amdgcn_mfma_f32_16x16x32_bf16(a, b, acc[t], 0, 0, 0);
        }
    }

#pragma unroll
    for (int t = 0; t < 8; ++t) {
#pragma unroll
        for (int r = 0; r < 4; ++r) {
            const int row = m0 + quad * 4 + r;
            if (row < N_NODES) hb[(size_t)row * HID + t * 16 + ln] = f2b(acc[t][r]);
        }
    }
}

// ====== split-row agg: 512 threads, 8 waves; TWO 16-lane groups per row.
// FUSE (layer 1): h = raw hb, per-edge dinv weights; epilogue GEMM2 output PRE-SCALED
//                 by dinv[orow] -> hb2 holds dinv*y@W2.
// !FUSE (layer 2): h = pre-scaled hb2 -> inner loop is a PURE gather-sum (no cursor
//                  loads, no rsqrt); v = dd*(acc + h[row]) + b.
template <bool FUSE>
__device__ __forceinline__ void agg_body(const int* __restrict__ cursor,
                                         const int* __restrict__ esrc,
                                         const unsigned short* __restrict__ h,
                                         const float* __restrict__ bia,
                                         const float* __restrict__ g,
                                         const float* __restrict__ be,
                                         const unsigned short* __restrict__ WT2,
                                         unsigned short* __restrict__ hb2,
                                         float* __restrict__ outf) {
    __shared__ float pbuf[2048];                   // 16 rows x 128 f32 partials; reused as bf16 tile
    const int tid  = threadIdx.x;
    const int wv   = tid >> 6;                     // 0..7
    const int lane = tid & 63;
    const int grp  = lane >> 4;
    const int fl   = lane & 15;
    const int half = wv >> 2;                      // 0 or 1: which half of the edge list
    const int r    = (wv & 3) * 4 + grp;           // row within block, 0..15
    const int row  = blockIdx.x * 16 + r;          // 3125*16 == 50000 exactly

    const int cntA  = cursor[row];                 // true in-degree
    const int cnt   = cntA < MAXDEG ? cntA : MAXDEG;
    const int ebase = row * MAXDEG;
    const int c0    = ((cnt + 7) >> 3) << 2;       // half0 size, multiple of 4
    const int h0n   = c0 < cnt ? c0 : cnt;
    const int eb    = half ? ebase + h0n : ebase;  // half1 start is 16B-aligned
    const int ee    = half ? ebase + cnt : ebase + h0n;

    float acc[8];
#pragma unroll
    for (int j = 0; j < 8; ++j) acc[j] = 0.f;

    int e = eb;
    for (; e + 3 < ee; e += 4) {
        const int4 s4 = *(const int4*)(esrc + e);
        const short8 v0 = *(const short8*)(h + (size_t)s4.x * HID + 8 * fl);
        const short8 v1 = *(const short8*)(h + (size_t)s4.y * HID + 8 * fl);
        const short8 v2 = *(const short8*)(h + (size_t)s4.z * HID + 8 * fl);
        const short8 v3 = *(const short8*)(h + (size_t)s4.w * HID + 8 * fl);
        if constexpr (FUSE) {
            const float w0 = rsqrtf((float)cursor[s4.x] + 1.0f);
            const float w1 = rsqrtf((float)cursor[s4.y] + 1.0f);
            const float w2 = rsqrtf((float)cursor[s4.z] + 1.0f);
            const float w3 = rsqrtf((float)cursor[s4.w] + 1.0f);
#pragma unroll
            for (int j = 0; j < 8; ++j) {
                acc[j] = fmaf(w0, b2f((unsigned short)v0[j]), acc[j]);
                acc[j] = fmaf(w1, b2f((unsigned short)v1[j]), acc[j]);
                acc[j] = fmaf(w2, b2f((unsigned short)v2[j]), acc[j]);
                acc[j] = fmaf(w3, b2f((unsigned short)v3[j]), acc[j]);
            }
        } else {
#pragma unroll
            for (int j = 0; j < 8; ++j) {
                acc[j] += b2f((unsigned short)v0[j]) + b2f((unsigned short)v1[j]);
                acc[j] += b2f((unsigned short)v2[j]) + b2f((unsigned short)v3[j]);
            }
        }
    }
    for (; e < ee; ++e) {                          // <=3 tail edges (half0 only)
        const int sA = esrc[e];
        const short8 vA = *(const short8*)(h + (size_t)sA * HID + 8 * fl);
        float wA = 1.0f;
        if constexpr (FUSE) wA = rsqrtf((float)cursor[sA] + 1.0f);
#pragma unroll
        for (int j = 0; j < 8; ++j)
            acc[j] = fmaf(wA, b2f((unsigned short)vA[j]), acc[j]);
    }

    // merge half1's partial into half0 via LDS (once per row)
    if (half == 1) {
#pragma unroll
        for (int j = 0; j < 8; ++j) pbuf[r * 128 + 8 * fl + j] = acc[j];
    }
    __syncthreads();

    float o[8];
    if (half == 0) {
#pragma unroll
        for (int j = 0; j < 8; ++j) acc[j] += pbuf[r * 128 + 8 * fl + j];

        const float dd = rsqrtf((float)cntA + 1.0f);
        const short8 hv = *(const short8*)(h + (size_t)row * HID + 8 * fl);
        const float4 b0 = *(const float4*)(bia + 8 * fl);
        const float4 b1 = *(const float4*)(bia + 8 * fl + 4);
        const float bb[8] = {b0.x, b0.y, b0.z, b0.w, b1.x, b1.y, b1.z, b1.w};

        float v[8], s = 0.f, ss = 0.f;
#pragma unroll
        for (int j = 0; j < 8; ++j) {
            if constexpr (FUSE) {
                const float sn = dd * dd;
                v[j] = dd * acc[j] + b2f((unsigned short)hv[j]) * sn + bb[j];
            } else {
                // h pre-scaled: self term raw*dd^2 == h_scaled*dd
                v[j] = dd * (acc[j] + b2f((unsigned short)hv[j])) + bb[j];
            }
            s += v[j];
            ss = fmaf(v[j], v[j], ss);
        }
#pragma unroll
        for (int off = 1; off <= 8; off <<= 1) {   // LN stats across the 16 feature lanes
            s  += __shfl_xor(s, off);
            ss += __shfl_xor(ss, off);
        }
        const float mu  = s * (1.0f / 128.0f);
        const float var = ss * (1.0f / 128.0f) - mu * mu;
        const float rs  = rsqrtf(var + LN_EPS);

        const float4 g0  = *(const float4*)(g + 8 * fl);
        const float4 g1  = *(const float4*)(g + 8 * fl + 4);
        const float4 e0v = *(const float4*)(be + 8 * fl);
        const float4 e1v = *(const float4*)(be + 8 * fl + 4);
        const float gg[8] = {g0.x, g0.y, g0.z, g0.w, g1.x, g1.y, g1.z, g1.w};
        const float ee2[8] = {e0v.x, e0v.y, e0v.z, e0v.w, e1v.x, e1v.y, e1v.z, e1v.w};
#pragma unroll
        for (int j = 0; j < 8; ++j)
            o[j] = fmaxf((v[j] - mu) * rs * gg[j] + ee2[j], 0.0f);
    }

    if constexpr (!FUSE) {
        if (half == 0) {
            float4 w0 = {o[0], o[1], o[2], o[3]};
            float4 w1 = {o[4], o[5], o[6], o[7]};
            *(float4*)(outf + (size_t)row * HID + 8 * fl) = w0;
            *(float4*)(outf + (size_t)row * HID + 8 * fl + 4) = w1;
        }
    } else {
        __syncthreads();                           // all pbuf reads done before tile overwrite
        unsigned short* tile = (unsigned short*)pbuf;
        if (half == 0) {
            short8 w;
#pragma unroll
            for (int j = 0; j < 8; ++j) w[j] = (short)f2b(o[j]);
            *(short8*)&tile[r * 128 + ((8 * fl) ^ ((r & 7) << 3))] = w;
        }
        __syncthreads();

        // 8 waves x 16 output cols; output PRE-SCALED by dinv[orow]
        f32x4 c = (f32x4){0.f, 0.f, 0.f, 0.f};
        const int n0 = wv * 16 + fl;
#pragma unroll
        for (int ks = 0; ks < 4; ++ks) {
            const short8 a  = *(const short8*)&tile[fl * 128 + ((grp * 8 + ks * 32) ^ ((fl & 7) << 3))];
            const short8 bf = *(const short8*)(WT2 + (size_t)n0 * HID + grp * 8 + ks * 32);
            c = __builtin_amdgcn_mfma_f32_16x16x32_bf16(a, bf, c, 0, 0, 0);
        }
#pragma unroll
        for (int rr = 0; rr < 4; ++rr) {
            const int orow = blockIdx.x * 16 + grp * 4 + rr;
            const float sc = rsqrtf((float)cursor[orow] + 1.0f);
            hb2[(size_t)orow * HID + n0] = f2b(c[rr] * sc);
        }
    }
}

__global__ __launch_bounds__(512, 4) void k_agg_fuse(const int* __restrict__ cursor,
                                                     const int* __restrict__ esrc,
                                                     const unsigned short* __restrict__ h,
                                                     const float* __restrict__ bia,
                                                     const float* __restrict__ g,
                                                     const float* __restrict__ be,
                                                     const unsigned short* __restrict__ WT2,
                                                     unsigned short* __restrict__ hb2) {
    agg_body<true>(cursor, esrc, h, bia, g, be, WT2, hb2, nullptr);
}

__global__ __launch_bounds__(512, 4) void k_agg_out(const int* __restrict__ cursor,
                                                    const int* __restrict__ esrc,
                                                    const unsigned short* __restrict__ h,
                                                    const float* __restrict__ bia,
                                                    const float* __restrict__ g,
                                                    const float* __restrict__ be,
                                                    float* __restrict__ outf) {
    agg_body<false>(cursor, esrc, h, bia, g, be, nullptr, nullptr, outf);
}

// ================= launch =================
extern "C" void kernel_launch(void* const* d_in, const int* in_sizes, int n_in,
                              void* d_out, int out_size, void* d_ws, size_t ws_size,
                              hipStream_t stream) {
    (void)in_sizes; (void)n_in; (void)out_size; (void)ws_size;

    const float* x   = (const float*)d_in[0];
    const int*   ei  = (const int*)d_in[1];     // [2,E]: src = ei[e], dst = ei[E+e]
    const float* W1  = (const float*)d_in[2];
    const float* b1  = (const float*)d_in[3];
    const float* g1  = (const float*)d_in[4];
    const float* be1 = (const float*)d_in[5];
    const float* W2  = (const float*)d_in[6];
    const float* b2  = (const float*)d_in[7];
    const float* g2  = (const float*)d_in[8];
    const float* be2 = (const float*)d_in[9];
    float* out = (float*)d_out;

    // workspace layout (dword offsets)
    int* cursor = (int*)d_ws;                              // [0, 50000) degree/slot cursor
    int* esrc   = (int*)d_ws + 50016;                      // 50000*64 = 3.2M dwords -> [50016, 3250016)
    unsigned short* WT1 = (unsigned short*)((int*)d_ws + 3250016);  // 8192 dwords -> [3250016, 3258208)
    unsigned short* WT2 = (unsigned short*)((int*)d_ws + 3258208);  // 8192 dwords -> [3258208, 3266400)
    unsigned short* hb  = (unsigned short*)((int*)d_ws + 3266400);  // 3.2M dwords -> [3266400, 6466400)
    unsigned short* hb2 = (unsigned short*)((int*)d_ws + 6466400);  // 3.2M dwords -> [6466400, 9666400)

    // prep: weight conversion + cursor zero (replaces the memset dispatch)
    k_prep<<<324, 256, 0, stream>>>(W1, W2, WT1, WT2, cursor);
    // GEMM1 (B from L2-hot global WT1) + edge placement, no LDS
    k_fused1<<<NB_GEMM1 + NB_PLACE, 256, 0, stream>>>(x, WT1, ei, cursor, esrc, hb);

    // layer 1 agg/LN/ReLU fused with layer-2 GEMM -> hb2 (bf16, pre-scaled by dinv)
    k_agg_fuse<<<N_NODES / 16, 512, 0, stream>>>(cursor, esrc, hb, b1, g1, be1, WT2, hb2);
    // layer 2 agg/LN/ReLU -> out (fp32); pure gather-sum inner loop
    k_agg_out<<<N_NODES / 16, 512, 0, stream>>>(cursor, esrc, hb2, b2, g2, be2, out);
}

// Round 8
// 193.397 us; speedup vs baseline: 1.1057x; 1.1057x over previous
//
#include <hip/hip_runtime.h>

#define N_NODES 50000
#define N_EDGES 600000
#define HID 128
#define LN_EPS 1e-5f
#define MAXDEG 64
#define NT_GEMM 782     // ceil(50000/64) m-tiles
#define NB_GEMM 160     // GEMM blocks (grid-stride over tiles; stage W1 once each)
#define NB_PLACE 2344   // ceil(600000/256)

typedef __attribute__((ext_vector_type(8))) short short8;
typedef __attribute__((ext_vector_type(4))) float f32x4;

__device__ inline float b2f(unsigned short u) {
    union { unsigned int i; float f; } v;
    v.i = ((unsigned int)u) << 16;
    return v.f;
}
__device__ inline unsigned short f2b(float f) {   // round-to-nearest-even
    union { float f; unsigned int u; } v; v.f = f;
    unsigned int r = (v.u + 0x7FFFu + ((v.u >> 16) & 1u)) >> 16;
    return (unsigned short)r;
}

// ================= K1: GEMM1 (blocks [0,160), LDS-staged W1, grid-stride tiles)
//                     + edge PLACE + W2->bf16^T (blocks [160, 160+2344)) =================
__global__ __launch_bounds__(256) void k_fused1(const float* __restrict__ x,
                                                const float* __restrict__ W1,
                                                const float* __restrict__ W2,
                                                const int* __restrict__ ei,
                                                int* __restrict__ cursor,
                                                int* __restrict__ esrc,
                                                unsigned short* __restrict__ WT2,
                                                unsigned short* __restrict__ hb) {
    const int tid = threadIdx.x;

    if (blockIdx.x >= NB_GEMM) {
        const int bi = blockIdx.x - NB_GEMM;
        const int e = bi * 256 + tid;
        if (e < N_EDGES) {
            const int d = ei[N_EDGES + e];
            const int pos = atomicAdd(&cursor[d], 1);
            if (pos < MAXDEG) esrc[d * MAXDEG + pos] = ei[e];
        }
        if (bi < 64) {
            const int i = bi * 256 + tid;          // 16384 W2 elements
            WT2[(i & 127) * 128 + (i >> 7)] = f2b(W2[i]);
        }
        return;
    }

    // ---- stage W1 fp32 -> LDS bf16^T, XOR-swizzled (ONCE per block, ~5 tiles amortize it) ----
    __shared__ unsigned short wt[16384];
    {
        const float4* W4 = (const float4*)W1;
#pragma unroll
        for (int it = 0; it < 16; ++it) {
            const int i4 = tid + 256 * it;         // 4096 float4s total
            const float4 v = W4[i4];
            const int k  = (i4 * 4) >> 7;
            const int n0 = (i4 * 4) & 127;
            wt[(n0 + 0) * 128 + (k ^ (((n0 + 0) & 7) << 3))] = f2b(v.x);
            wt[(n0 + 1) * 128 + (k ^ (((n0 + 1) & 7) << 3))] = f2b(v.y);
            wt[(n0 + 2) * 128 + (k ^ (((n0 + 2) & 7) << 3))] = f2b(v.z);
            wt[(n0 + 3) * 128 + (k ^ (((n0 + 3) & 7) << 3))] = f2b(v.w);
        }
    }
    __syncthreads();

    const int lane = tid & 63;
    const int ln   = lane & 15;
    const int quad = lane >> 4;

    for (int mt = blockIdx.x; mt < NT_GEMM; mt += NB_GEMM) {
        const int m0 = mt * 64 + (tid >> 6) * 16;

        f32x4 acc[8];
#pragma unroll
        for (int t = 0; t < 8; ++t) acc[t] = (f32x4){0.f, 0.f, 0.f, 0.f};

        int arow = m0 + ln;
        if (arow >= N_NODES) arow = N_NODES - 1;
        const float* aptr = x + (size_t)arow * HID + quad * 8;

#pragma unroll
        for (int ks = 0; ks < 4; ++ks) {
            const float4 v0 = *(const float4*)(aptr + ks * 32);
            const float4 v1 = *(const float4*)(aptr + ks * 32 + 4);
            short8 a;
            a[0] = (short)f2b(v0.x); a[1] = (short)f2b(v0.y);
            a[2] = (short)f2b(v0.z); a[3] = (short)f2b(v0.w);
            a[4] = (short)f2b(v1.x); a[5] = (short)f2b(v1.y);
            a[6] = (short)f2b(v1.z); a[7] = (short)f2b(v1.w);
#pragma unroll
            for (int t = 0; t < 8; ++t) {
                const int n = t * 16 + ln;
                const short8 b = *(const short8*)&wt[n * 128 + ((quad * 8 + ks * 32) ^ ((n & 7) << 3))];
                acc[t] = __builtin_amdgcn_mfma_f32_16x16x32_bf16(a, b, acc[t], 0, 0, 0);
            }
        }

#pragma unroll
        for (int t = 0; t < 8; ++t) {
#pragma unroll
            for (int r = 0; r < 4; ++r) {
                const int row = m0 + quad * 4 + r;
                if (row < N_NODES) hb[(size_t)row * HID + t * 16 + ln] = f2b(acc[t][r]);
            }
        }
    }
}

// ====== split-row agg: 512 threads, 8 waves; TWO 16-lane groups per row.
// FUSE (layer 1): h = raw hb, per-edge dinv weights; epilogue GEMM2 output PRE-SCALED
//                 by dinv[orow] -> hb2 holds dinv*y@W2.
// !FUSE (layer 2): h = pre-scaled hb2 -> inner loop is a PURE gather-sum.
template <bool FUSE>
__device__ __forceinline__ void agg_body(const int* __restrict__ cursor,
                                         const int* __restrict__ esrc,
                                         const unsigned short* __restrict__ h,
                                         const float* __restrict__ bia,
                                         const float* __restrict__ g,
                                         const float* __restrict__ be,
                                         const unsigned short* __restrict__ WT2,
                                         unsigned short* __restrict__ hb2,
                                         float* __restrict__ outf) {
    __shared__ float pbuf[2048];                   // 16 rows x 128 f32 partials; reused as bf16 tile
    const int tid  = threadIdx.x;
    const int wv   = tid >> 6;                     // 0..7
    const int lane = tid & 63;
    const int grp  = lane >> 4;
    const int fl   = lane & 15;
    const int half = wv >> 2;                      // 0 or 1: which half of the edge list
    const int r    = (wv & 3) * 4 + grp;           // row within block, 0..15
    const int row  = blockIdx.x * 16 + r;          // 3125*16 == 50000 exactly

    const int cntA  = cursor[row];                 // true in-degree
    const int cnt   = cntA < MAXDEG ? cntA : MAXDEG;
    const int ebase = row * MAXDEG;
    const int c0    = ((cnt + 7) >> 3) << 2;       // half0 size, multiple of 4
    const int h0n   = c0 < cnt ? c0 : cnt;
    const int eb    = half ? ebase + h0n : ebase;  // half1 start is 16B-aligned
    const int ee    = half ? ebase + cnt : ebase + h0n;

    float acc[8];
#pragma unroll
    for (int j = 0; j < 8; ++j) acc[j] = 0.f;

    int e = eb;
    for (; e + 3 < ee; e += 4) {
        const int4 s4 = *(const int4*)(esrc + e);
        const short8 v0 = *(const short8*)(h + (size_t)s4.x * HID + 8 * fl);
        const short8 v1 = *(const short8*)(h + (size_t)s4.y * HID + 8 * fl);
        const short8 v2 = *(const short8*)(h + (size_t)s4.z * HID + 8 * fl);
        const short8 v3 = *(const short8*)(h + (size_t)s4.w * HID + 8 * fl);
        if constexpr (FUSE) {
            const float w0 = rsqrtf((float)cursor[s4.x] + 1.0f);
            const float w1 = rsqrtf((float)cursor[s4.y] + 1.0f);
            const float w2 = rsqrtf((float)cursor[s4.z] + 1.0f);
            const float w3 = rsqrtf((float)cursor[s4.w] + 1.0f);
#pragma unroll
            for (int j = 0; j < 8; ++j) {
                acc[j] = fmaf(w0, b2f((unsigned short)v0[j]), acc[j]);
                acc[j] = fmaf(w1, b2f((unsigned short)v1[j]), acc[j]);
                acc[j] = fmaf(w2, b2f((unsigned short)v2[j]), acc[j]);
                acc[j] = fmaf(w3, b2f((unsigned short)v3[j]), acc[j]);
            }
        } else {
#pragma unroll
            for (int j = 0; j < 8; ++j) {
                acc[j] += b2f((unsigned short)v0[j]) + b2f((unsigned short)v1[j]);
                acc[j] += b2f((unsigned short)v2[j]) + b2f((unsigned short)v3[j]);
            }
        }
    }
    for (; e < ee; ++e) {                          // <=3 tail edges (half0 only)
        const int sA = esrc[e];
        const short8 vA = *(const short8*)(h + (size_t)sA * HID + 8 * fl);
        float wA = 1.0f;
        if constexpr (FUSE) wA = rsqrtf((float)cursor[sA] + 1.0f);
#pragma unroll
        for (int j = 0; j < 8; ++j)
            acc[j] = fmaf(wA, b2f((unsigned short)vA[j]), acc[j]);
    }

    // merge half1's partial into half0 via LDS (once per row)
    if (half == 1) {
#pragma unroll
        for (int j = 0; j < 8; ++j) pbuf[r * 128 + 8 * fl + j] = acc[j];
    }
    __syncthreads();

    float o[8];
    if (half == 0) {
#pragma unroll
        for (int j = 0; j < 8; ++j) acc[j] += pbuf[r * 128 + 8 * fl + j];

        const float dd = rsqrtf((float)cntA + 1.0f);
        const short8 hv = *(const short8*)(h + (size_t)row * HID + 8 * fl);
        const float4 b0 = *(const float4*)(bia + 8 * fl);
        const float4 b1 = *(const float4*)(bia + 8 * fl + 4);
        const float bb[8] = {b0.x, b0.y, b0.z, b0.w, b1.x, b1.y, b1.z, b1.w};

        float v[8], s = 0.f, ss = 0.f;
#pragma unroll
        for (int j = 0; j < 8; ++j) {
            if constexpr (FUSE) {
                const float sn = dd * dd;
                v[j] = dd * acc[j] + b2f((unsigned short)hv[j]) * sn + bb[j];
            } else {
                v[j] = dd * (acc[j] + b2f((unsigned short)hv[j])) + bb[j];
            }
            s += v[j];
            ss = fmaf(v[j], v[j], ss);
        }
#pragma unroll
        for (int off = 1; off <= 8; off <<= 1) {   // LN stats across the 16 feature lanes
            s  += __shfl_xor(s, off);
            ss += __shfl_xor(ss, off);
        }
        const float mu  = s * (1.0f / 128.0f);
        const float var = ss * (1.0f / 128.0f) - mu * mu;
        const float rs  = rsqrtf(var + LN_EPS);

        const float4 g0  = *(const float4*)(g + 8 * fl);
        const float4 g1  = *(const float4*)(g + 8 * fl + 4);
        const float4 e0v = *(const float4*)(be + 8 * fl);
        const float4 e1v = *(const float4*)(be + 8 * fl + 4);
        const float gg[8] = {g0.x, g0.y, g0.z, g0.w, g1.x, g1.y, g1.z, g1.w};
        const float ee2[8] = {e0v.x, e0v.y, e0v.z, e0v.w, e1v.x, e1v.y, e1v.z, e1v.w};
#pragma unroll
        for (int j = 0; j < 8; ++j)
            o[j] = fmaxf((v[j] - mu) * rs * gg[j] + ee2[j], 0.0f);
    }

    if constexpr (!FUSE) {
        if (half == 0) {
            float4 w0 = {o[0], o[1], o[2], o[3]};
            float4 w1 = {o[4], o[5], o[6], o[7]};
            *(float4*)(outf + (size_t)row * HID + 8 * fl) = w0;
            *(float4*)(outf + (size_t)row * HID + 8 * fl + 4) = w1;
        }
    } else {
        __syncthreads();                           // all pbuf reads done before tile overwrite
        unsigned short* tile = (unsigned short*)pbuf;
        if (half == 0) {
            short8 w;
#pragma unroll
            for (int j = 0; j < 8; ++j) w[j] = (short)f2b(o[j]);
            *(short8*)&tile[r * 128 + ((8 * fl) ^ ((r & 7) << 3))] = w;
        }
        __syncthreads();

        // 8 waves x 16 output cols; output PRE-SCALED by dinv[orow]
        f32x4 c = (f32x4){0.f, 0.f, 0.f, 0.f};
        const int n0 = wv * 16 + fl;
#pragma unroll
        for (int ks = 0; ks < 4; ++ks) {
            const short8 a  = *(const short8*)&tile[fl * 128 + ((grp * 8 + ks * 32) ^ ((fl & 7) << 3))];
            const short8 bf = *(const short8*)(WT2 + (size_t)n0 * HID + grp * 8 + ks * 32);
            c = __builtin_amdgcn_mfma_f32_16x16x32_bf16(a, bf, c, 0, 0, 0);
        }
#pragma unroll
        for (int rr = 0; rr < 4; ++rr) {
            const int orow = blockIdx.x * 16 + grp * 4 + rr;
            const float sc = rsqrtf((float)cursor[orow] + 1.0f);
            hb2[(size_t)orow * HID + n0] = f2b(c[rr] * sc);
        }
    }
}

__global__ __launch_bounds__(512, 4) void k_agg_fuse(const int* __restrict__ cursor,
                                                     const int* __restrict__ esrc,
                                                     const unsigned short* __restrict__ h,
                                                     const float* __restrict__ bia,
                                                     const float* __restrict__ g,
                                                     const float* __restrict__ be,
                                                     const unsigned short* __restrict__ WT2,
                                                     unsigned short* __restrict__ hb2) {
    agg_body<true>(cursor, esrc, h, bia, g, be, WT2, hb2, nullptr);
}

__global__ __launch_bounds__(512, 4) void k_agg_out(const int* __restrict__ cursor,
                                                    const int* __restrict__ esrc,
                                                    const unsigned short* __restrict__ h,
                                                    const float* __restrict__ bia,
                                                    const float* __restrict__ g,
                                                    const float* __restrict__ be,
                                                    float* __restrict__ outf) {
    agg_body<false>(cursor, esrc, h, bia, g, be, nullptr, nullptr, outf);
}

// ================= launch =================
extern "C" void kernel_launch(void* const* d_in, const int* in_sizes, int n_in,
                              void* d_out, int out_size, void* d_ws, size_t ws_size,
                              hipStream_t stream) {
    (void)in_sizes; (void)n_in; (void)out_size; (void)ws_size;

    const float* x   = (const float*)d_in[0];
    const int*   ei  = (const int*)d_in[1];     // [2,E]: src = ei[e], dst = ei[E+e]
    const float* W1  = (const float*)d_in[2];
    const float* b1  = (const float*)d_in[3];
    const float* g1  = (const float*)d_in[4];
    const float* be1 = (const float*)d_in[5];
    const float* W2  = (const float*)d_in[6];
    const float* b2  = (const float*)d_in[7];
    const float* g2  = (const float*)d_in[8];
    const float* be2 = (const float*)d_in[9];
    float* out = (float*)d_out;

    // workspace layout (dword offsets)
    int* cursor = (int*)d_ws;                              // [0, 50000) degree/slot cursor
    int* esrc   = (int*)d_ws + 50016;                      // 50000*64 = 3.2M dwords -> [50016, 3250016)
    unsigned short* WT2 = (unsigned short*)((int*)d_ws + 3250016);  // 8192 dwords -> [3250016, 3258208)
    unsigned short* hb  = (unsigned short*)((int*)d_ws + 3258208);  // 3.2M dwords -> [3258208, 6458208)
    unsigned short* hb2 = (unsigned short*)((int*)d_ws + 6458208);  // 3.2M dwords -> [6458208, 9658208)

    // zero the slot cursors, then: GEMM1 (grid-stride, amortized staging) + place + W2conv
    hipMemsetAsync(cursor, 0, N_NODES * sizeof(int), stream);
    k_fused1<<<NB_GEMM + NB_PLACE, 256, 0, stream>>>(x, W1, W2, ei, cursor, esrc, WT2, hb);

    // layer 1 agg/LN/ReLU fused with layer-2 GEMM -> hb2 (bf16, pre-scaled by dinv)
    k_agg_fuse<<<N_NODES / 16, 512, 0, stream>>>(cursor, esrc, hb, b1, g1, be1, WT2, hb2);
    // layer 2 agg/LN/ReLU -> out (fp32); pure gather-sum inner loop
    k_agg_out<<<N_NODES / 16, 512, 0, stream>>>(cursor, esrc, hb2, b2, g2, be2, out);
}